// Round 13
// baseline (123.353 us; speedup 1.0000x reference)
//
#include <hip/hip_runtime.h>
#include <math.h>

#define BB 4
#define SQL 512
#define SKL 512
#define HH 256
#define AA 128

// 2 * log2(e): prep stores Qt/Kt as Eq=2^(PRESCALE*qt), Ek=2^(PRESCALE*kt).
#define PRESCALE 2.8853900817779268f
#define LOG2E    1.4426950408889634f

__device__ inline void fma4(float4& a, float s, const float4& b) {
    a.x = fmaf(s, b.x, a.x); a.y = fmaf(s, b.y, a.y);
    a.z = fmaf(s, b.z, a.z); a.w = fmaf(s, b.w, a.w);
}

// DPP add: x + dpp_move(x). Stays on the VALU pipe (no ds_swizzle / lgkm).
template <int CTRL>
__device__ __forceinline__ float dpp_add(float x) {
    int m = __builtin_amdgcn_update_dpp(__float_as_int(x), __float_as_int(x),
                                        CTRL, 0xF, 0xF, false);
    return x + __int_as_float(m);
}
// Sum over each aligned 16-lane group (one DPP row).
__device__ __forceinline__ float red16(float x) {
    x = dpp_add<0xB1>(x);
    x = dpp_add<0x4E>(x);
    x = dpp_add<0x141>(x);
    x = dpp_add<0x140>(x);
    return x;
}

#define PIN4(V) asm volatile("" : "+v"((V).x), "+v"((V).y), "+v"((V).z), "+v"((V).w))

// ---------------------------------------------------------------------------
// Kernel 1 "prep": Qt = exp2(PRESCALE*(Q@W_q)), Kt = exp2(PRESCALE*(K@W_k)),
// VW = V@W_o. (unchanged)
// ---------------------------------------------------------------------------
__global__ __launch_bounds__(256) void prep_kernel(
    const float* __restrict__ Q, const float* __restrict__ K,
    const float* __restrict__ V,
    const float* __restrict__ Wq, const float* __restrict__ Wk,
    const float* __restrict__ Wo,
    float* __restrict__ Qt, float* __restrict__ Kt, float* __restrict__ VW)
{
    __shared__ float rows[16 * HH];    // 16 KB
    __shared__ float wl[64 * 128];     // 32 KB
    int tid = threadIdx.x;
    int bid = blockIdx.x;

    const float* X; const float* W; float* Y;
    int ldW, ldY, col0, r0; float scale;
    if (bid < 128)      { X=Q; W=Wq; Y=Qt; ldW=AA; ldY=AA; col0=0; r0=bid*16;       scale=PRESCALE; }
    else if (bid < 256) { X=K; W=Wk; Y=Kt; ldW=AA; ldY=AA; col0=0; r0=(bid-128)*16; scale=PRESCALE; }
    else { int b2=bid-256; X=V; W=Wo; Y=VW; ldW=HH; ldY=HH; col0=(b2&1)*128; r0=(b2>>1)*16; scale=1.0f; }

    {
        const float4* Xv = (const float4*)(X + (size_t)r0 * HH);
        float4* rv = (float4*)rows;
        rv[tid]       = Xv[tid];
        rv[tid + 256] = Xv[tid + 256];
        rv[tid + 512] = Xv[tid + 512];
        rv[tid + 768] = Xv[tid + 768];
    }

    int r  = tid >> 5;
    int c4 = tid & 31;
    float4 accA = {0.f,0.f,0.f,0.f}, accB = {0.f,0.f,0.f,0.f};

    for (int ch = 0; ch < 4; ++ch) {
        __syncthreads();
        {
            const float* Wbase = W + (size_t)(ch * 64) * ldW + col0;
            float4* wv = (float4*)wl;
            #pragma unroll
            for (int it = 0; it < 8; ++it) {
                int l = tid + it * 256;
                wv[l] = *(const float4*)(Wbase + (size_t)(l >> 5) * ldW + ((l & 31) << 2));
            }
        }
        __syncthreads();
        const float* rrowA = rows + r * HH + ch * 64;
        const float* rrowB = rows + (r + 8) * HH + ch * 64;
        #pragma unroll 4
        for (int h4 = 0; h4 < 16; ++h4) {
            float4 ra = *(const float4*)(rrowA + h4 * 4);
            float4 rb = *(const float4*)(rrowB + h4 * 4);
            const float* wbase = wl + (h4 * 4) * 128 + (c4 << 2);
            float4 w0 = *(const float4*)(wbase);
            float4 w1 = *(const float4*)(wbase + 128);
            float4 w2 = *(const float4*)(wbase + 256);
            float4 w3 = *(const float4*)(wbase + 384);
            fma4(accA, ra.x, w0); fma4(accA, ra.y, w1);
            fma4(accA, ra.z, w2); fma4(accA, ra.w, w3);
            fma4(accB, rb.x, w0); fma4(accB, rb.y, w1);
            fma4(accB, rb.z, w2); fma4(accB, rb.w, w3);
        }
    }
    accA.x *= scale; accA.y *= scale; accA.z *= scale; accA.w *= scale;
    accB.x *= scale; accB.y *= scale; accB.z *= scale; accB.w *= scale;
    if (bid < 256) {   // Qt/Kt: store exp2 form
        accA.x = __builtin_amdgcn_exp2f(accA.x); accA.y = __builtin_amdgcn_exp2f(accA.y);
        accA.z = __builtin_amdgcn_exp2f(accA.z); accA.w = __builtin_amdgcn_exp2f(accA.w);
        accB.x = __builtin_amdgcn_exp2f(accB.x); accB.y = __builtin_amdgcn_exp2f(accB.y);
        accB.z = __builtin_amdgcn_exp2f(accB.z); accB.w = __builtin_amdgcn_exp2f(accB.w);
    }
    *(float4*)(Y + (size_t)(r0 + r)     * ldY + col0 + (c4 << 2)) = accA;
    *(float4*)(Y + (size_t)(r0 + r + 8) * ldY + col0 + (c4 << 2)) = accB;
}

// ---------------------------------------------------------------------------
// Kernel 2a "scores": scores + softmax -> weights. DIAGNOSTIC SPLIT of the
// R12 score_kernel: same structure, epilogue removed. Its dur_us isolates the
// main-loop + softmax cost that has been invariant at ~44 us for 12 rounds.
// ---------------------------------------------------------------------------
#define FORQ(OP) OP(0) OP(1) OP(2) OP(3) OP(4) OP(5) OP(6) OP(7)

__global__ __launch_bounds__(512)
__attribute__((amdgpu_waves_per_eu(2, 2)))
void scores_kernel(
    const float* __restrict__ Qt, const float* __restrict__ Kt,
    const float* __restrict__ v,
    float* __restrict__ weights)
{
    __shared__ float score[8][SKL];      // 16 KB only

    int tid = threadIdx.x;
    int b  = blockIdx.x >> 6;            // 64 blocks per batch
    int q0 = (blockIdx.x & 63) << 3;     // 8 q-rows per block
    int ag = tid & 15;                   // a-range [8ag, 8ag+8)
    int kl = tid >> 4;                   // k within 32-chunk (0..31)

    float4 v2a, v2b;
    {
        const float4* vp = (const float4*)(v + ag * 8);
        v2a = vp[0]; v2b = vp[1];
        v2a.x *= 2.f; v2a.y *= 2.f; v2a.z *= 2.f; v2a.w *= 2.f;
        v2b.x *= 2.f; v2b.y *= 2.f; v2b.z *= 2.f; v2b.w *= 2.f;
        PIN4(v2a); PIN4(v2b);
    }

#define DECL_EQ(Qi) float4 EqA##Qi, EqB##Qi;
    FORQ(DECL_EQ)
#define LOAD_EQ(Qi) { \
        const float4* qp = (const float4*)(Qt + (size_t)(b * SQL + q0 + Qi) * AA + ag * 8); \
        (EqA##Qi) = qp[0]; (EqB##Qi) = qp[1]; \
        PIN4(EqA##Qi); PIN4(EqB##Qi); }
    FORQ(LOAD_EQ)

    float S_all;
    {
        float ls = (v2a.x + v2a.y) + (v2a.z + v2a.w)
                 + (v2b.x + v2b.y) + (v2b.z + v2b.w);
        S_all = 0.5f * red16(ls);
    }

    const float4* ktp = (const float4*)(Kt + (size_t)b * SKL * AA);

    {
        float4 ka = ktp[(size_t)kl * (AA / 4) + ag * 2];
        float4 kb = ktp[(size_t)kl * (AA / 4) + ag * 2 + 1];
        #pragma unroll 1
        for (int c = 0; c < 16; ++c) {
            float4 na, nb;
            if (c < 15) {
                int kn = (c + 1) * 32 + kl;
                na = ktp[(size_t)kn * (AA / 4) + ag * 2];
                nb = ktp[(size_t)kn * (AA / 4) + ag * 2 + 1];
            }
#define DECL_P(Qi) float p##Qi = 0.f;
            FORQ(DECL_P)
#define STEPC(KE, VE, HB, COMP) { \
            float Ek = KE; \
            p0 = fmaf(VE, __builtin_amdgcn_rcpf(fmaf(Ek, (Eq##HB##0).COMP, 1.0f)), p0); \
            p1 = fmaf(VE, __builtin_amdgcn_rcpf(fmaf(Ek, (Eq##HB##1).COMP, 1.0f)), p1); \
            p2 = fmaf(VE, __builtin_amdgcn_rcpf(fmaf(Ek, (Eq##HB##2).COMP, 1.0f)), p2); \
            p3 = fmaf(VE, __builtin_amdgcn_rcpf(fmaf(Ek, (Eq##HB##3).COMP, 1.0f)), p3); \
            p4 = fmaf(VE, __builtin_amdgcn_rcpf(fmaf(Ek, (Eq##HB##4).COMP, 1.0f)), p4); \
            p5 = fmaf(VE, __builtin_amdgcn_rcpf(fmaf(Ek, (Eq##HB##5).COMP, 1.0f)), p5); \
            p6 = fmaf(VE, __builtin_amdgcn_rcpf(fmaf(Ek, (Eq##HB##6).COMP, 1.0f)), p6); \
            p7 = fmaf(VE, __builtin_amdgcn_rcpf(fmaf(Ek, (Eq##HB##7).COMP, 1.0f)), p7); }
            STEPC(ka.x, v2a.x, A, x) STEPC(ka.y, v2a.y, A, y)
            STEPC(ka.z, v2a.z, A, z) STEPC(ka.w, v2a.w, A, w)
            STEPC(kb.x, v2b.x, B, x) STEPC(kb.y, v2b.y, B, y)
            STEPC(kb.z, v2b.z, B, z) STEPC(kb.w, v2b.w, B, w)
#define RED_P(Qi) p##Qi = red16(p##Qi);
            FORQ(RED_P)
            if (ag == 0) {
                int k = c * 32 + kl;
#define STORE_P(Qi) score[Qi][k] = (S_all - p##Qi) * LOG2E;
                FORQ(STORE_P)
            }
            ka = na; kb = nb;
        }
    }
    __syncthreads();

    // ---- softmax (no max pass) -> weights (global) ----
    int wave = tid >> 6, lane = tid & 63;
    {
        int qi = wave;
        float ssum = 0.f;
        #pragma unroll
        for (int it = 0; it < 2; ++it) {
            int k0 = it * 256 + (lane << 2);
            float4 sv = *(float4*)&score[qi][k0];
            sv.x = __builtin_amdgcn_exp2f(sv.x);
            sv.y = __builtin_amdgcn_exp2f(sv.y);
            sv.z = __builtin_amdgcn_exp2f(sv.z);
            sv.w = __builtin_amdgcn_exp2f(sv.w);
            *(float4*)&score[qi][k0] = sv;
            ssum += (sv.x + sv.y) + (sv.z + sv.w);
        }
        #pragma unroll
        for (int off = 32; off; off >>= 1) ssum += __shfl_xor(ssum, off);
        float rinv = 1.0f / ssum;
        size_t rowoff = (size_t)(b * SQL + q0 + qi) * SKL;
        #pragma unroll
        for (int it = 0; it < 2; ++it) {
            int k0 = it * 256 + (lane << 2);
            float4 sv = *(float4*)&score[qi][k0];
            sv.x *= rinv; sv.y *= rinv; sv.z *= rinv; sv.w *= rinv;
            *(float4*)(weights + rowoff + k0) = sv;
        }
    }
}

// ---------------------------------------------------------------------------
// Kernel 2b "epilogue": out = weights @ VW + b_o. Same block mapping and
// inner structure as the R12 epilogue phase; weights staged via LDS.
// ---------------------------------------------------------------------------
__global__ __launch_bounds__(512) void epilogue_kernel(
    const float* __restrict__ weights, const float* __restrict__ VW,
    const float* __restrict__ bo,
    float* __restrict__ out)
{
    __shared__ float score[8][SKL];      // 16 KB
    __shared__ float pout[8][4][HH];     // 32 KB

    int tid = threadIdx.x;
    int b  = blockIdx.x >> 6;
    int q0 = (blockIdx.x & 63) << 3;
    int wave = tid >> 6, lane = tid & 63;

    // stage the 8 weight rows (8x512 floats, contiguous) into LDS
    {
        const float4* wr = (const float4*)(weights + (size_t)(b * SQL + q0) * SKL);
        float4* sv = (float4*)score;
        sv[tid]       = wr[tid];
        sv[tid + 512] = wr[tid + 512];
    }
    __syncthreads();

#define DECL_ACC(Qi) float4 acc##Qi = {0.f, 0.f, 0.f, 0.f};
    FORQ(DECL_ACC)
    {
        const float4* VWb = (const float4*)(VW + (size_t)b * SKL * HH);
        int kbase = wave * 64;
        #pragma unroll 2
        for (int k4 = 0; k4 < 16; ++k4) {
            int kk = kbase + k4 * 4;
#define DECL_W(Qi) float4 w##Qi = *(const float4*)&score[Qi][kk];
            FORQ(DECL_W)
            float4 vw;
            vw = VWb[(size_t)(kk + 0) * (HH / 4) + lane];
#define FMA_X(Qi) fma4(acc##Qi, (w##Qi).x, vw);
            FORQ(FMA_X)
            vw = VWb[(size_t)(kk + 1) * (HH / 4) + lane];
#define FMA_Y(Qi) fma4(acc##Qi, (w##Qi).y, vw);
            FORQ(FMA_Y)
            vw = VWb[(size_t)(kk + 2) * (HH / 4) + lane];
#define FMA_Z(Qi) fma4(acc##Qi, (w##Qi).z, vw);
            FORQ(FMA_Z)
            vw = VWb[(size_t)(kk + 3) * (HH / 4) + lane];
#define FMA_W(Qi) fma4(acc##Qi, (w##Qi).w, vw);
            FORQ(FMA_W)
        }
    }

    int h  = tid & 255;
    int qh = tid >> 8;
    float bias = bo[h];

    *(float4*)&pout[wave][0][lane << 2] = acc0;
    *(float4*)&pout[wave][1][lane << 2] = acc1;
    *(float4*)&pout[wave][2][lane << 2] = acc2;
    *(float4*)&pout[wave][3][lane << 2] = acc3;
    __syncthreads();
    #pragma unroll
    for (int qq = 0; qq < 2; ++qq) {
        int qi = qh * 2 + qq;
        float s = bias;
        #pragma unroll
        for (int w2 = 0; w2 < 8; ++w2) s += pout[w2][qi][h];
        out[(size_t)(b * SQL + q0 + qi) * HH + h] = s;
    }
    __syncthreads();

    *(float4*)&pout[wave][0][lane << 2] = acc4;
    *(float4*)&pout[wave][1][lane << 2] = acc5;
    *(float4*)&pout[wave][2][lane << 2] = acc6;
    *(float4*)&pout[wave][3][lane << 2] = acc7;
    __syncthreads();
    #pragma unroll
    for (int qq = 0; qq < 2; ++qq) {
        int qi = qh * 2 + qq;
        float s = bias;
        #pragma unroll
        for (int w2 = 0; w2 < 8; ++w2) s += pout[w2][qi][h];
        out[(size_t)(b * SQL + q0 + 4 + qi) * HH + h] = s;
    }
}

// ---------------------------------------------------------------------------
extern "C" void kernel_launch(void* const* d_in, const int* in_sizes, int n_in,
                              void* d_out, int out_size, void* d_ws, size_t ws_size,
                              hipStream_t stream)
{
    const float* Q  = (const float*)d_in[0];
    const float* K  = (const float*)d_in[1];
    const float* V  = (const float*)d_in[2];
    const float* Wq = (const float*)d_in[3];
    const float* Wk = (const float*)d_in[4];
    const float* v  = (const float*)d_in[5];
    const float* Wo = (const float*)d_in[6];
    const float* bo = (const float*)d_in[7];

    float* out     = (float*)d_out;                   // (B,SQ,H) = 524288
    float* weights = out + (size_t)BB * SQL * HH;     // (B,SQ,SK) = 1048576

    float* Qt = (float*)d_ws;                         // 262144 floats
    float* Kt = Qt + (size_t)BB * SQL * AA;           // 262144 floats
    float* VW = Kt + (size_t)BB * SKL * AA;           // 524288 floats

    prep_kernel    <<<512, 256, 0, stream>>>(Q, K, V, Wq, Wk, Wo, Qt, Kt, VW);
    scores_kernel  <<<256, 512, 0, stream>>>(Qt, Kt, v, weights);
    epilogue_kernel<<<256, 512, 0, stream>>>(weights, VW, bo, out);
}

// Round 14
// 118.746 us; speedup vs baseline: 1.0388x; 1.0388x over previous
//
#include <hip/hip_runtime.h>
#include <math.h>

#define BB 4
#define SQL 512
#define SKL 512
#define HH 256
#define AA 128

// prep stores Qt/Kt as Eq=2^(PRESCALE*qt), Ek=2^(PRESCALE*kt); PRESCALE=2*log2(e).
#define PRESCALE 2.8853900817779268f
#define LOG2E    1.4426950408889634f

__device__ inline void fma4(float4& a, float s, const float4& b) {
    a.x = fmaf(s, b.x, a.x); a.y = fmaf(s, b.y, a.y);
    a.z = fmaf(s, b.z, a.z); a.w = fmaf(s, b.w, a.w);
}

// DPP add: x + dpp_move(x). Stays on the VALU pipe.
template <int CTRL>
__device__ __forceinline__ float dpp_add(float x) {
    int m = __builtin_amdgcn_update_dpp(__float_as_int(x), __float_as_int(x),
                                        CTRL, 0xF, 0xF, false);
    return x + __int_as_float(m);
}
// Sum over each aligned 16-lane group (one DPP row).
__device__ __forceinline__ float red16(float x) {
    x = dpp_add<0xB1>(x);
    x = dpp_add<0x4E>(x);
    x = dpp_add<0x141>(x);
    x = dpp_add<0x140>(x);
    return x;
}

#define PIN4(V) asm volatile("" : "+v"((V).x), "+v"((V).y), "+v"((V).z), "+v"((V).w))

// ---------------------------------------------------------------------------
// Kernel 1 "prep": Qt = exp2(PRESCALE*(Q@W_q)), Kt = exp2(PRESCALE*(K@W_k)),
// VW = V@W_o. (unchanged, verified)
// ---------------------------------------------------------------------------
__global__ __launch_bounds__(256) void prep_kernel(
    const float* __restrict__ Q, const float* __restrict__ K,
    const float* __restrict__ V,
    const float* __restrict__ Wq, const float* __restrict__ Wk,
    const float* __restrict__ Wo,
    float* __restrict__ Qt, float* __restrict__ Kt, float* __restrict__ VW)
{
    __shared__ float rows[16 * HH];    // 16 KB
    __shared__ float wl[64 * 128];     // 32 KB
    int tid = threadIdx.x;
    int bid = blockIdx.x;

    const float* X; const float* W; float* Y;
    int ldW, ldY, col0, r0; float scale;
    if (bid < 128)      { X=Q; W=Wq; Y=Qt; ldW=AA; ldY=AA; col0=0; r0=bid*16;       scale=PRESCALE; }
    else if (bid < 256) { X=K; W=Wk; Y=Kt; ldW=AA; ldY=AA; col0=0; r0=(bid-128)*16; scale=PRESCALE; }
    else { int b2=bid-256; X=V; W=Wo; Y=VW; ldW=HH; ldY=HH; col0=(b2&1)*128; r0=(b2>>1)*16; scale=1.0f; }

    {
        const float4* Xv = (const float4*)(X + (size_t)r0 * HH);
        float4* rv = (float4*)rows;
        rv[tid]       = Xv[tid];
        rv[tid + 256] = Xv[tid + 256];
        rv[tid + 512] = Xv[tid + 512];
        rv[tid + 768] = Xv[tid + 768];
    }

    int r  = tid >> 5;
    int c4 = tid & 31;
    float4 accA = {0.f,0.f,0.f,0.f}, accB = {0.f,0.f,0.f,0.f};

    for (int ch = 0; ch < 4; ++ch) {
        __syncthreads();
        {
            const float* Wbase = W + (size_t)(ch * 64) * ldW + col0;
            float4* wv = (float4*)wl;
            #pragma unroll
            for (int it = 0; it < 8; ++it) {
                int l = tid + it * 256;
                wv[l] = *(const float4*)(Wbase + (size_t)(l >> 5) * ldW + ((l & 31) << 2));
            }
        }
        __syncthreads();
        const float* rrowA = rows + r * HH + ch * 64;
        const float* rrowB = rows + (r + 8) * HH + ch * 64;
        #pragma unroll 4
        for (int h4 = 0; h4 < 16; ++h4) {
            float4 ra = *(const float4*)(rrowA + h4 * 4);
            float4 rb = *(const float4*)(rrowB + h4 * 4);
            const float* wbase = wl + (h4 * 4) * 128 + (c4 << 2);
            float4 w0 = *(const float4*)(wbase);
            float4 w1 = *(const float4*)(wbase + 128);
            float4 w2 = *(const float4*)(wbase + 256);
            float4 w3 = *(const float4*)(wbase + 384);
            fma4(accA, ra.x, w0); fma4(accA, ra.y, w1);
            fma4(accA, ra.z, w2); fma4(accA, ra.w, w3);
            fma4(accB, rb.x, w0); fma4(accB, rb.y, w1);
            fma4(accB, rb.z, w2); fma4(accB, rb.w, w3);
        }
    }
    accA.x *= scale; accA.y *= scale; accA.z *= scale; accA.w *= scale;
    accB.x *= scale; accB.y *= scale; accB.z *= scale; accB.w *= scale;
    if (bid < 256) {   // Qt/Kt: store exp2 form
        accA.x = __builtin_amdgcn_exp2f(accA.x); accA.y = __builtin_amdgcn_exp2f(accA.y);
        accA.z = __builtin_amdgcn_exp2f(accA.z); accA.w = __builtin_amdgcn_exp2f(accA.w);
        accB.x = __builtin_amdgcn_exp2f(accB.x); accB.y = __builtin_amdgcn_exp2f(accB.y);
        accB.z = __builtin_amdgcn_exp2f(accB.z); accB.w = __builtin_amdgcn_exp2f(accB.w);
    }
    *(float4*)(Y + (size_t)(r0 + r)     * ldY + col0 + (c4 << 2)) = accA;
    *(float4*)(Y + (size_t)(r0 + r + 8) * ldY + col0 + (c4 << 2)) = accB;
}

// ---------------------------------------------------------------------------
// Kernel 2 (fused again): scores + softmax + (weights @ VW + b_o).
// R14: 4 q-rows/block (Eq = 32 floats -> total live ~75, FITS the allocator's
// observed 88-VGPR envelope: no spill/remat possible), grid 512 blocks
// (2 blocks/CU, 16 waves/CU). 13 rounds showed time invariant at ~44us while
// issue-ops/trans/occupancy swung 1.7-4.5x; the surviving explanation is
// in-loop spill traffic from 8q's oversized Eq state. This tests it.
//   score[q][k] = S_all - sum_a 2*v[a] / (Ek*Eq + 1),  Ek/Eq pre-exp2'd.
// ---------------------------------------------------------------------------
#define FORQ4(OP) OP(0) OP(1) OP(2) OP(3)

__global__ __launch_bounds__(512) void score_kernel(
    const float* __restrict__ Qt, const float* __restrict__ Kt,
    const float* __restrict__ v,  const float* __restrict__ VW,
    const float* __restrict__ bo,
    float* __restrict__ weights,  float* __restrict__ out)
{
    __shared__ float score[4][SKL];      // 8 KB
    __shared__ float pout[8][4][HH];     // 32 KB
    __shared__ float ssums[2][4];        //      (total ~40 KB)

    int tid = threadIdx.x;
    int b  = blockIdx.x >> 7;            // 128 blocks per batch
    int q0 = (blockIdx.x & 127) << 2;    // 4 q-rows per block
    int ag = tid & 15;                   // a-range [8ag, 8ag+8)
    int kl = tid >> 4;                   // k within 32-chunk (0..31)

    // 2*v fragment
    float4 v2a, v2b;
    {
        const float4* vp = (const float4*)(v + ag * 8);
        v2a = vp[0]; v2b = vp[1];
        v2a.x *= 2.f; v2a.y *= 2.f; v2a.z *= 2.f; v2a.w *= 2.f;
        v2b.x *= 2.f; v2b.y *= 2.f; v2b.z *= 2.f; v2b.w *= 2.f;
        PIN4(v2a); PIN4(v2b);
    }

    // Eq: 4 q-rows x 8 a -> 8 named float4 (pre-exp2'd by prep), pinned live.
#define DECL_EQ(Qi) float4 EqA##Qi, EqB##Qi;
    FORQ4(DECL_EQ)
#define LOAD_EQ(Qi) { \
        const float4* qp = (const float4*)(Qt + (size_t)(b * SQL + q0 + Qi) * AA + ag * 8); \
        (EqA##Qi) = qp[0]; (EqB##Qi) = qp[1]; \
        PIN4(EqA##Qi); PIN4(EqB##Qi); }
    FORQ4(LOAD_EQ)

    // S_all = sum_a v[a]
    float S_all;
    {
        float ls = (v2a.x + v2a.y) + (v2a.z + v2a.w)
                 + (v2b.x + v2b.y) + (v2b.z + v2b.w);
        S_all = 0.5f * red16(ls);
    }

    const float4* ktp = (const float4*)(Kt + (size_t)b * SKL * AA);

    // ---- main loop: 16 chunks x 32 k-rows; named-reg prefetch ----
    {
        float4 ka = ktp[(size_t)kl * (AA / 4) + ag * 2];
        float4 kb = ktp[(size_t)kl * (AA / 4) + ag * 2 + 1];
        #pragma unroll 1
        for (int c = 0; c < 16; ++c) {
            float4 na, nb;
            if (c < 15) {
                int kn = (c + 1) * 32 + kl;
                na = ktp[(size_t)kn * (AA / 4) + ag * 2];
                nb = ktp[(size_t)kn * (AA / 4) + ag * 2 + 1];
            }
            float p0 = 0.f, p1 = 0.f, p2 = 0.f, p3 = 0.f;
#define STEPC(KE, VE, HB, COMP) { \
            float Ek = KE; \
            p0 = fmaf(VE, __builtin_amdgcn_rcpf(fmaf(Ek, (Eq##HB##0).COMP, 1.0f)), p0); \
            p1 = fmaf(VE, __builtin_amdgcn_rcpf(fmaf(Ek, (Eq##HB##1).COMP, 1.0f)), p1); \
            p2 = fmaf(VE, __builtin_amdgcn_rcpf(fmaf(Ek, (Eq##HB##2).COMP, 1.0f)), p2); \
            p3 = fmaf(VE, __builtin_amdgcn_rcpf(fmaf(Ek, (Eq##HB##3).COMP, 1.0f)), p3); }
            STEPC(ka.x, v2a.x, A, x) STEPC(ka.y, v2a.y, A, y)
            STEPC(ka.z, v2a.z, A, z) STEPC(ka.w, v2a.w, A, w)
            STEPC(kb.x, v2b.x, B, x) STEPC(kb.y, v2b.y, B, y)
            STEPC(kb.z, v2b.z, B, z) STEPC(kb.w, v2b.w, B, w)
            p0 = red16(p0); p1 = red16(p1); p2 = red16(p2); p3 = red16(p3);
            if (ag == 0) {
                int k = c * 32 + kl;
                score[0][k] = (S_all - p0) * LOG2E;
                score[1][k] = (S_all - p1) * LOG2E;
                score[2][k] = (S_all - p2) * LOG2E;
                score[3][k] = (S_all - p3) * LOG2E;
            }
            ka = na; kb = nb;
        }
    }
    __syncthreads();

    // ---- softmax: 8 waves = 4 q-rows x 2 halves (no max pass; |score| bounded) ----
    int wave = tid >> 6, lane = tid & 63;
    int qi = wave & 3;                   // q-row
    int kh = wave >> 2;                  // half: k in [256*kh, 256*kh+256)
    {
        int k0 = kh * 256 + (lane << 2);
        float4 sv = *(float4*)&score[qi][k0];
        sv.x = __builtin_amdgcn_exp2f(sv.x);
        sv.y = __builtin_amdgcn_exp2f(sv.y);
        sv.z = __builtin_amdgcn_exp2f(sv.z);
        sv.w = __builtin_amdgcn_exp2f(sv.w);
        *(float4*)&score[qi][k0] = sv;
        float ssum = (sv.x + sv.y) + (sv.z + sv.w);
        #pragma unroll
        for (int off = 32; off; off >>= 1) ssum += __shfl_xor(ssum, off);
        if (lane == 0) ssums[kh][qi] = ssum;
    }
    __syncthreads();
    {
        float rinv = 1.0f / (ssums[0][qi] + ssums[1][qi]);
        int k0 = kh * 256 + (lane << 2);
        float4 sv = *(float4*)&score[qi][k0];
        sv.x *= rinv; sv.y *= rinv; sv.z *= rinv; sv.w *= rinv;
        *(float4*)&score[qi][k0] = sv;
        size_t rowoff = (size_t)(b * SQL + q0 + qi) * SKL;
        *(float4*)(weights + rowoff + k0) = sv;
    }
    __syncthreads();

    // ---- epilogue: wave w owns k in [64w, 64w+64); one VW pass serves 4 q ----
    float4 acc0 = {0,0,0,0}, acc1 = {0,0,0,0}, acc2 = {0,0,0,0}, acc3 = {0,0,0,0};
    {
        const float4* VWb = (const float4*)(VW + (size_t)b * SKL * HH);
        int kbase = wave * 64;
        #pragma unroll 2
        for (int k4 = 0; k4 < 16; ++k4) {
            int kk = kbase + k4 * 4;
            float4 w0 = *(const float4*)&score[0][kk];
            float4 w1 = *(const float4*)&score[1][kk];
            float4 w2 = *(const float4*)&score[2][kk];
            float4 w3 = *(const float4*)&score[3][kk];
            float4 vw;
            vw = VWb[(size_t)(kk + 0) * (HH / 4) + lane];
            fma4(acc0, w0.x, vw); fma4(acc1, w1.x, vw); fma4(acc2, w2.x, vw); fma4(acc3, w3.x, vw);
            vw = VWb[(size_t)(kk + 1) * (HH / 4) + lane];
            fma4(acc0, w0.y, vw); fma4(acc1, w1.y, vw); fma4(acc2, w2.y, vw); fma4(acc3, w3.y, vw);
            vw = VWb[(size_t)(kk + 2) * (HH / 4) + lane];
            fma4(acc0, w0.z, vw); fma4(acc1, w1.z, vw); fma4(acc2, w2.z, vw); fma4(acc3, w3.z, vw);
            vw = VWb[(size_t)(kk + 3) * (HH / 4) + lane];
            fma4(acc0, w0.w, vw); fma4(acc1, w1.w, vw); fma4(acc2, w2.w, vw); fma4(acc3, w3.w, vw);
        }
    }

    *(float4*)&pout[wave][0][lane << 2] = acc0;
    *(float4*)&pout[wave][1][lane << 2] = acc1;
    *(float4*)&pout[wave][2][lane << 2] = acc2;
    *(float4*)&pout[wave][3][lane << 2] = acc3;
    __syncthreads();
    {
        int h  = tid & 255;
        int qh = tid >> 8;               // 0 or 1
        float bias = bo[h];
        #pragma unroll
        for (int qq = 0; qq < 2; ++qq) {
            int qi2 = qh * 2 + qq;       // 0..3
            float s = bias;
            #pragma unroll
            for (int w2 = 0; w2 < 8; ++w2) s += pout[w2][qi2][h];
            out[(size_t)(b * SQL + q0 + qi2) * HH + h] = s;
        }
    }
}

// ---------------------------------------------------------------------------
extern "C" void kernel_launch(void* const* d_in, const int* in_sizes, int n_in,
                              void* d_out, int out_size, void* d_ws, size_t ws_size,
                              hipStream_t stream)
{
    const float* Q  = (const float*)d_in[0];
    const float* K  = (const float*)d_in[1];
    const float* V  = (const float*)d_in[2];
    const float* Wq = (const float*)d_in[3];
    const float* Wk = (const float*)d_in[4];
    const float* v  = (const float*)d_in[5];
    const float* Wo = (const float*)d_in[6];
    const float* bo = (const float*)d_in[7];

    float* out     = (float*)d_out;                   // (B,SQ,H) = 524288
    float* weights = out + (size_t)BB * SQL * HH;     // (B,SQ,SK) = 1048576

    float* Qt = (float*)d_ws;                         // 262144 floats
    float* Kt = Qt + (size_t)BB * SQL * AA;           // 262144 floats
    float* VW = Kt + (size_t)BB * SKL * AA;           // 524288 floats

    prep_kernel <<<512, 256, 0, stream>>>(Q, K, V, Wq, Wk, Wo, Qt, Kt, VW);
    score_kernel<<<512, 512, 0, stream>>>(Qt, Kt, v, VW, bo, weights, out);
}